// Round 6
// baseline (1277.418 us; speedup 1.0000x reference)
//
#include <hip/hip_runtime.h>

#define BB 2
#define FF 2
#define CC 3
#define HH 256
#define WW 512
#define DD 32
#define HW (HH*WW)
#define CV_SIZE (BB*DD*HW)

#define SH 16                 // output rows per block
#define NSTRIP (HH/SH)        // 16
#define HALFW 256             // columns per wave (half image width)
#define INV9 (1.0f/9.0f)
#define C1f 1e-4f
#define C2f 9e-4f

__device__ __forceinline__ int refl(int i, int n) { return i < 0 ? -i : (i >= n ? 2*n-2-i : i); }

// 4x4 Gauss-Jordan inverse with partial pivoting (f32, matches jnp.linalg.inv)
__device__ void inv4(const float* m, float* out) {
  float a[4][8];
  for (int i = 0; i < 4; ++i)
    for (int j = 0; j < 4; ++j) { a[i][j] = m[i*4+j]; a[i][j+4] = (i==j) ? 1.f : 0.f; }
  for (int col = 0; col < 4; ++col) {
    int piv = col; float best = fabsf(a[col][col]);
    for (int r = col+1; r < 4; ++r) { float v = fabsf(a[r][col]); if (v > best) { best = v; piv = r; } }
    if (piv != col) for (int j = 0; j < 8; ++j) { float t = a[col][j]; a[col][j] = a[piv][j]; a[piv][j] = t; }
    float invd = 1.0f / a[col][col];
    for (int j = 0; j < 8; ++j) a[col][j] *= invd;
    for (int r = 0; r < 4; ++r) {
      if (r == col) continue;
      float f = a[r][col];
      for (int j = 0; j < 8; ++j) a[r][j] -= f * a[col][j];
    }
  }
  for (int i = 0; i < 4; ++i) for (int j = 0; j < 4; ++j) out[i*4+j] = a[i][j+4];
}

// IK (3x3 inv intrinsics), P (3x4 proj), M[fb][d] = depth*P[:,:3]*IK (+P[:,3] in col 2)
__global__ void setup_kernel(const float* __restrict__ kK, const float* __restrict__ Ks,
                             const float* __restrict__ kpose, const float* __restrict__ poses,
                             float* __restrict__ P, float* __restrict__ IK, float* __restrict__ M) {
  __shared__ float sIK[BB][9];
  __shared__ float sP[FF*BB][12];
  int t = threadIdx.x;
  if (t < BB) {
    float inv[16]; inv4(kK + t*16, inv);
    float* o = IK + t*9;
    float v0=inv[0], v1=inv[1], v2=inv[2], v3=inv[4], v4=inv[5], v5=inv[6], v6=inv[8], v7=inv[9], v8=inv[10];
    o[0]=v0;o[1]=v1;o[2]=v2;o[3]=v3;o[4]=v4;o[5]=v5;o[6]=v6;o[7]=v7;o[8]=v8;
    sIK[t][0]=v0;sIK[t][1]=v1;sIK[t][2]=v2;sIK[t][3]=v3;sIK[t][4]=v4;sIK[t][5]=v5;sIK[t][6]=v6;sIK[t][7]=v7;sIK[t][8]=v8;
  }
  if (t >= 32 && t < 32 + FF*BB) {
    int i = t - 32;               // i = f*BB + b
    int b = i % BB;
    float ip[16]; inv4(poses + i*16, ip);
    float T[16];
    for (int r = 0; r < 4; ++r)
      for (int c = 0; c < 4; ++c) {
        float s = 0.f;
        for (int k = 0; k < 4; ++k) s += ip[r*4+k] * kpose[b*16 + k*4 + c];
        T[r*4+c] = s;
      }
    for (int r = 0; r < 3; ++r)
      for (int c = 0; c < 4; ++c) {
        float s = 0.f;
        for (int k = 0; k < 4; ++k) s += Ks[i*16 + r*4 + k] * T[k*4 + c];
        P[i*12 + r*4 + c] = s;
        sP[i][r*4+c] = s;
      }
  }
  __syncthreads();
  if (t < FF*BB*DD) {             // 128 matrices
    int fb = t / DD, d = t % DD, b = fb % BB;
    const float invd0 = 1.0f/3.0f;
    const float step  = (0.0125f - (1.0f/3.0f)) / 31.0f;
    float depth = 1.0f / (invd0 + step * (float)d);
    for (int i = 0; i < 3; ++i)
      for (int j = 0; j < 3; ++j) {
        float s = sP[fb][i*4+0]*sIK[b][0*3+j] + sP[fb][i*4+1]*sIK[b][1*3+j] + sP[fb][i*4+2]*sIK[b][2*3+j];
        float mv = depth*s + ((j==2) ? sP[fb][i*4+3] : 0.f);
        M[t*12 + i*3 + j] = mv;
      }
  }
}

struct F3 { float v[CC]; };

// bilinear-sample one column (3 channels) at projected position; returns value+0.5
__device__ __forceinline__ F3 sample_col(const float* __restrict__ frame,
    float m00, float m10, float m20, float b0, float b1, float b2, float fw) {
  float cp0 = fmaf(m00, fw, b0);
  float cp1 = fmaf(m10, fw, b1);
  float cp2 = fmaf(m20, fw, b2);
  float den = cp2 + 1e-7f;
  float rd = __builtin_amdgcn_rcpf(den);
  float px = cp0*rd, py = cp1*rd;
  float gx = fminf(fmaxf((px*(1.0f/511.0f) - 0.5f)*2.0f, -2.0f), 2.0f);
  float gy = fminf(fmaxf((py*(1.0f/255.0f) - 0.5f)*2.0f, -2.0f), 2.0f);
  float x = (gx + 1.0f)*((float)WW*0.5f) - 0.5f;
  float y = (gy + 1.0f)*((float)HH*0.5f) - 0.5f;
  float x0f = floorf(x), y0f = floorf(y);
  float x1f = x0f + 1.f, y1f = y0f + 1.f;
  float wa = (x1f-x)*(y1f-y);
  float wb = (x1f-x)*(y-y0f);
  float wc = (x-x0f)*(y1f-y);
  float wd = (x-x0f)*(y-y0f);
  bool vx0 = (x0f >= 0.f) && (x0f <= (float)(WW-1));
  bool vx1 = (x1f >= 0.f) && (x1f <= (float)(WW-1));
  bool vy0 = (y0f >= 0.f) && (y0f <= (float)(HH-1));
  bool vy1 = (y1f >= 0.f) && (y1f <= (float)(HH-1));
  int xi0 = (int)fminf(fmaxf(x0f, 0.f), (float)(WW-1));
  int xi1 = (int)fminf(fmaxf(x1f, 0.f), (float)(WW-1));
  int yi0 = (int)fminf(fmaxf(y0f, 0.f), (float)(HH-1));
  int yi1 = (int)fminf(fmaxf(y1f, 0.f), (float)(HH-1));
  int i00 = yi0*WW + xi0, i01 = yi1*WW + xi0;
  int i10 = yi0*WW + xi1, i11 = yi1*WW + xi1;
  F3 o;
  #pragma unroll
  for (int c = 0; c < CC; ++c) {
    const float* im = frame + c*HW;
    float va = (vx0 && vy0) ? im[i00] : 0.f;
    float vb2 = (vx0 && vy1) ? im[i01] : 0.f;
    float vc2 = (vx1 && vy0) ? im[i10] : 0.f;
    float vd2 = (vx1 && vy1) ? im[i11] : 0.f;
    o.v[c] = fmaf(va, wa, fmaf(vb2, wb, fmaf(vc2, wc, vd2*wd))) + 0.5f;
  }
  return o;
}

__device__ __forceinline__ float ssim_term(float hx, float hxx, float hxy, float mu_y, float sg_y) {
  float mux = hx*INV9;
  float sigx = fmaf(-mux, mux, hxx*INV9);
  float sigxy = fmaf(-mux, mu_y, hxy*INV9);
  float nn  = (2.f*mux*mu_y + C1f) * (2.f*sigxy + C2f);
  float ddn = fmaf(mux, mux, fmaf(mu_y, mu_y, C1f)) * ((sigx + sg_y) + C2f);
  float v = (1.f - nn*__builtin_amdgcn_rcpf(ddn))*0.5f;
  return fminf(fmaxf(v, 0.f), 1.f);
}

// Fused warp+SSIM+box-sum: one 64-lane wave per (fb, d, strip, half). No LDS, no barriers.
// x AND keyframe-y rolling windows in registers (1 new row of each per iter);
// mu_y/sigma_y computed INLINE from the y window (no precomputed arrays, no re-reads).
// blockIdx swizzle: (half,d) in low bits so blocks sharing keyframe rows co-schedule.
__global__ __launch_bounds__(64, 3) void wss4_kernel(
    const float* __restrict__ frames, const float* __restrict__ keyframe,
    const float* __restrict__ M, float* __restrict__ sadout) {
  int bid = blockIdx.x;
  int half  = bid & 1;
  int d     = (bid >> 1) & (DD-1);
  int strip = (bid >> 6) & (NSTRIP-1);
  int fb    = bid >> 10;
  int b = fb % BB;
  int h0 = strip * SH;
  int l = threadIdx.x;
  int w0 = half*HALFW + l*4;
  int hc = half ? (255 - l) : (319 - l);   // halo col: meaningful lanes {0,1} / {62,63}

  const float* Mp = M + (fb*DD + d)*12;
  float m00=Mp[0], m01=Mp[1], m02=Mp[2];
  float m10=Mp[3], m11=Mp[4], m12=Mp[5];
  float m20=Mp[6], m21=Mp[7], m22=Mp[8];
  const float* frame = frames + (size_t)fb*CC*HW;
  const float* kfb   = keyframe + (size_t)b*CC*HW;
  float* sadp = sadout + (size_t)(fb*DD + d)*HW;

  float xr[CC][3][4], yr[CC][3][4];   // rolling windows (rows refl(r-1), refl(r), refl(r+1))
  float hxr[CC][3],   hyr[CC][3];     // halo col rolling windows
  float df[3][4], hdf[3];
  #pragma unroll
  for (int k = 0; k < 4; ++k) { df[0][k]=0.f; df[1][k]=0.f; df[2][k]=0.f; }
  hdf[0]=0.f; hdf[1]=0.f; hdf[2]=0.f;

  float fwk[4], fhc = (float)hc;
  #pragma unroll
  for (int k = 0; k < 4; ++k) fwk[k] = (float)(w0 + k);

#define SAMPLE_ROW(slot, hrarg) do { \
    int hr_ = (hrarg); \
    float fh_ = (float)hr_; \
    float b0_ = fmaf(m01, fh_, m02); \
    float b1_ = fmaf(m11, fh_, m12); \
    float b2_ = fmaf(m21, fh_, m22); \
    _Pragma("unroll") \
    for (int c_ = 0; c_ < CC; ++c_) { \
      const float4 yv_ = *(const float4*)(kfb + c_*HW + hr_*WW + w0); \
      yr[c_][slot][0] = yv_.x + 0.5f; yr[c_][slot][1] = yv_.y + 0.5f; \
      yr[c_][slot][2] = yv_.z + 0.5f; yr[c_][slot][3] = yv_.w + 0.5f; \
      hyr[c_][slot] = kfb[c_*HW + hr_*WW + hc] + 0.5f; \
    } \
    _Pragma("unroll") \
    for (int k_ = 0; k_ < 4; ++k_) { \
      F3 s_ = sample_col(frame, m00, m10, m20, b0_, b1_, b2_, fwk[k_]); \
      xr[0][slot][k_] = s_.v[0]; xr[1][slot][k_] = s_.v[1]; xr[2][slot][k_] = s_.v[2]; \
    } \
    { F3 s_ = sample_col(frame, m00, m10, m20, b0_, b1_, b2_, fhc); \
      hxr[0][slot] = s_.v[0]; hxr[1][slot] = s_.v[1]; hxr[2][slot] = s_.v[2]; } \
  } while (0)

// horizontal 3-sum for main 4 cols + halo col (seam via halo, image edges via reflect)
#define HS(v, hv, o, oh) do { \
    float L_ = __shfl_up((v)[3], 1); \
    float R_ = __shfl_down((v)[0], 1); \
    if (l == 0)  L_ = half ? (hv) : (v)[1]; \
    if (l == 63) R_ = half ? (v)[2] : (hv); \
    float p01_ = (v)[0]+(v)[1], p12_ = (v)[1]+(v)[2], p23_ = (v)[2]+(v)[3]; \
    (o)[0] = L_ + p01_; (o)[1] = p01_ + (v)[2]; \
    (o)[2] = p12_ + (v)[3]; (o)[3] = p23_ + R_; \
    float hL_ = half ? __shfl_down((hv), 1) : (v)[3]; \
    float hR_ = half ? (v)[0] : __shfl_up((hv), 1); \
    (oh) = (hL_ + (hv)) + hR_; \
  } while (0)

  SAMPLE_ROW(0, refl(h0-2, HH));
  SAMPLE_ROW(1, refl(h0-1, HH));

#define STORE_SAD(srow, VB, HVB) do { \
    float Lb_ = __shfl_up((VB)[3], 1); \
    float Rb_ = __shfl_down((VB)[0], 1); \
    if (l == 0)  Lb_ = half ? (HVB) : 0.f; \
    if (l == 63) Rb_ = half ? 0.f : (HVB); \
    float p01_ = (VB)[0]+(VB)[1], p12_ = (VB)[1]+(VB)[2], p23_ = (VB)[2]+(VB)[3]; \
    float4 o_; \
    o_.x = (Lb_ + p01_)*INV9; \
    o_.y = (p01_ + (VB)[2])*INV9; \
    o_.z = (p12_ + (VB)[3])*INV9; \
    o_.w = (p23_ + Rb_)*INV9; \
    *(float4*)(sadp + (size_t)(srow)*WW + w0) = o_; \
  } while (0)

  #pragma unroll 1
  for (int i = 0; i < SH+2; ++i) {
    int r = h0 - 1 + i;
    // ---- sample row r+1 (window becomes rows r-1, r, r+1) ----
    SAMPLE_ROW(2, refl(r+1, HH));

    // ---- box sum for sad row r-2 (df window rows r-3..r-1, pre-rotation) ----
    int s = r - 2;
    if (s >= h0) {
      float vb[4];
      #pragma unroll
      for (int k = 0; k < 4; ++k) vb[k] = (df[0][k] + df[1][k]) + df[2][k];
      float hvb = (hdf[0] + hdf[1]) + hdf[2];
      STORE_SAD(s, vb, hvb);
    }

    // ---- rotate df; compute diff row r (per-channel, inline y-stats) ----
    #pragma unroll
    for (int k = 0; k < 4; ++k) { df[0][k] = df[1][k]; df[1][k] = df[2][k]; }
    hdf[0] = hdf[1]; hdf[1] = hdf[2];
    float nd[4] = {0.f,0.f,0.f,0.f};
    float hnd = 0.f;
    if (r >= 0 && r < HH) {
      #pragma unroll
      for (int c = 0; c < CC; ++c) {
        // vertical sums (x, x^2, x*y, y, y^2)
        float vsx[4], vsxx[4], vsxy[4], vsy[4], vsyy[4];
        #pragma unroll
        for (int k = 0; k < 4; ++k) {
          float x0 = xr[c][0][k], x1 = xr[c][1][k], x2 = xr[c][2][k];
          float y0 = yr[c][0][k], y1 = yr[c][1][k], y2 = yr[c][2][k];
          vsx[k]  = (x0 + x1) + x2;
          vsxx[k] = fmaf(x2, x2, fmaf(x1, x1, x0*x0));
          vsxy[k] = fmaf(x2, y2, fmaf(x1, y1, x0*y0));
          vsy[k]  = (y0 + y1) + y2;
          vsyy[k] = fmaf(y2, y2, fmaf(y1, y1, y0*y0));
        }
        float hx0=hxr[c][0], hx1=hxr[c][1], hx2=hxr[c][2];
        float hy0=hyr[c][0], hy1=hyr[c][1], hy2=hyr[c][2];
        float hvx  = (hx0 + hx1) + hx2;
        float hvxx = fmaf(hx2, hx2, fmaf(hx1, hx1, hx0*hx0));
        float hvxy = fmaf(hx2, hy2, fmaf(hx1, hy1, hx0*hy0));
        float hvy  = (hy0 + hy1) + hy2;
        float hvyy = fmaf(hy2, hy2, fmaf(hy1, hy1, hy0*hy0));

        // horizontal 3-sums
        float hsx[4], hsxx[4], hsxy[4], hsy[4], hsyy[4];
        float hhx, hhxx, hhxy, hhy, hhyy;
        HS(vsx,  hvx,  hsx,  hhx);
        HS(vsxx, hvxx, hsxx, hhxx);
        HS(vsxy, hvxy, hsxy, hhxy);
        HS(vsy,  hvy,  hsy,  hhy);
        HS(vsyy, hvyy, hsyy, hhyy);

        float cwc = (c==0) ? (5.f/32.f) : ((c==1) ? (16.f/32.f) : (11.f/32.f));
        #pragma unroll
        for (int k = 0; k < 4; ++k) {
          float mu_y = hsy[k]*INV9;
          float sg_y = fmaf(-mu_y, mu_y, hsyy[k]*INV9);
          nd[k] = fmaf(cwc, ssim_term(hsx[k], hsxx[k], hsxy[k], mu_y, sg_y), nd[k]);
        }
        float hmu = hhy*INV9;
        float hsg = fmaf(-hmu, hmu, hhyy*INV9);
        hnd = fmaf(cwc, ssim_term(hhx, hhxx, hhxy, hmu, hsg), hnd);
      }
    }
    df[2][0]=nd[0]; df[2][1]=nd[1]; df[2][2]=nd[2]; df[2][3]=nd[3];
    hdf[2] = hnd;

    // ---- rotate x/y windows ----
    #pragma unroll
    for (int c = 0; c < CC; ++c) {
      #pragma unroll
      for (int k = 0; k < 4; ++k) {
        xr[c][0][k]=xr[c][1][k]; xr[c][1][k]=xr[c][2][k];
        yr[c][0][k]=yr[c][1][k]; yr[c][1][k]=yr[c][2][k];
      }
      hxr[c][0]=hxr[c][1]; hxr[c][1]=hxr[c][2];
      hyr[c][0]=hyr[c][1]; hyr[c][1]=hyr[c][2];
    }
  }

  // ---- tail: sad row h0+SH-1 from df rows h0+SH-2..h0+SH ----
  {
    float vb[4];
    #pragma unroll
    for (int k = 0; k < 4; ++k) vb[k] = (df[0][k] + df[1][k]) + df[2][k];
    float hvb = (hdf[0] + hdf[1]) + hdf[2];
    STORE_SAD(h0+SH-1, vb, hvb);
  }
}

struct Proj { float x, y; };

__device__ __forceinline__ Proj project(const float* __restrict__ Pm,
                                        float camx, float camy, float camz, int d) {
  const float invd0 = 1.0f/3.0f;
  const float step  = (0.0125f - (1.0f/3.0f)) / 31.0f;
  float depth = 1.0f / (invd0 + step * (float)d);
  float X = depth*camx, Y = depth*camy, Z = depth*camz;
  float cp0 = Pm[0]*X + Pm[1]*Y + Pm[2]*Z  + Pm[3];
  float cp1 = Pm[4]*X + Pm[5]*Y + Pm[6]*Z  + Pm[7];
  float cp2 = Pm[8]*X + Pm[9]*Y + Pm[10]*Z + Pm[11];
  float den = cp2 + 1e-7f;
  float px = cp0 / den;
  float py = cp1 / den;
  float gx = px / (float)(WW-1);
  float gy = py / (float)(HH-1);
  gx = fminf(fmaxf((gx - 0.5f)*2.0f, -2.0f), 2.0f);
  gy = fminf(fmaxf((gy - 0.5f)*2.0f, -2.0f), 2.0f);
  Proj pr;
  pr.x = (gx + 1.0f) * ((float)WW*0.5f) - 0.5f;
  pr.y = (gy + 1.0f) * ((float)HH*0.5f) - 0.5f;
  return pr;
}

__device__ __forceinline__ float borderVal(float xif, float yif) {
  if (!((xif >= 0.f) && (xif <= (float)(WW-1)) && (yif >= 0.f) && (yif <= (float)(HH-1)))) return 0.f;
  int xi = (int)xif, yi = (int)yif;
  return (xi >= 2 && xi < WW-2 && yi >= 2 && yi < HH-2) ? 1.f : 0.f;
}

// Fused mask + weight + cost-volume + sfcv finalize. One thread = one (b, pixel).
__global__ __launch_bounds__(256) void final_kernel(
    const float* __restrict__ P, const float* __restrict__ IK,
    float* __restrict__ out) {
  int idx = blockIdx.x*blockDim.x + threadIdx.x;
  if (idx >= BB*HW) return;
  int p = idx % HW;
  int b = idx / HW;
  int w = p % WW, h = p / WW;
  float* sadbase = out + CV_SIZE;
  bool inb = (w >= 2 && w < WW-2 && h >= 2 && h < HH-2);

  float fw = (float)w, fh = (float)h;
  const float* ik = IK + b*9;
  float camx = ik[0]*fw + ik[1]*fh + ik[2];
  float camy = ik[3]*fw + ik[4]*fh + ik[5];
  float camz = ik[6]*fw + ik[7]*fh + ik[8];

  float cv[DD];
  #pragma unroll
  for (int d = 0; d < DD; ++d) cv[d] = 0.f;
  float wsum = 0.f;

  for (int f = 0; f < FF; ++f) {
    int fb = f*BB + b;
    const float* Pm = P + fb*12;
    bool ok = true;
    for (int d = 0; d < DD; ++d) {
      Proj pr = project(Pm, camx, camy, camz, d);
      float x = pr.x, y = pr.y;
      float x0f = floorf(x), y0f = floorf(y);
      float x1f = x0f+1.f, y1f = y0f+1.f;
      float wa = (x1f-x)*(y1f-y);
      float wb = (x1f-x)*(y-y0f);
      float wc = (x-x0f)*(y1f-y);
      float wd = (x-x0f)*(y-y0f);
      float m = borderVal(x0f,y0f)*wa + borderVal(x0f,y1f)*wb +
                borderVal(x1f,y0f)*wc + borderVal(x1f,y1f)*wd;
      ok = ok && (m != 0.f);
    }
    float wmask = (inb && ok) ? 1.f : 0.f;

    float* sfb = sadbase + (size_t)fb*DD*HW + p;
    float sv[DD];
    float mn = 3.0e38f;
    #pragma unroll
    for (int d = 0; d < DD; ++d) { sv[d] = sfb[(size_t)d*HW]; mn = fminf(mn, sv[d]); }
    float s = 0.f;
    #pragma unroll
    for (int d = 0; d < DD; ++d) { float tt = sv[d] - mn; s += __expf(-10.f*tt*tt); }
    float wt = (1.f - (s - 1.f)/31.f) * wmask;
    wsum += wt;
    #pragma unroll
    for (int d = 0; d < DD; ++d) {
      cv[d] += sv[d]*wt;
      sfb[(size_t)d*HW] = (1.f - 2.f*sv[d]) * wmask;   // sfcv in place
    }
  }
  #pragma unroll
  for (int d = 0; d < DD; ++d)
    out[((size_t)b*DD + d)*HW + p] = (wsum == 0.f) ? 0.f : 1.f - 2.f*cv[d]/wsum;
}

extern "C" void kernel_launch(void* const* d_in, const int* in_sizes, int n_in,
                              void* d_out, int out_size, void* d_ws, size_t ws_size,
                              hipStream_t stream) {
  const float* keyframe = (const float*)d_in[0];
  const float* frames   = (const float*)d_in[1];
  const float* kK       = (const float*)d_in[2];
  const float* Ks       = (const float*)d_in[3];
  const float* kpose    = (const float*)d_in[4];
  const float* poses    = (const float*)d_in[5];
  float* out = (float*)d_out;

  float* wsP   = (float*)d_ws;            // 48 floats (pad 64)
  float* wsIK  = wsP + 64;                // 18 floats (pad 64)
  float* wsM   = wsIK + 64;               // 128*12 floats

  setup_kernel<<<1, 128, 0, stream>>>(kK, Ks, kpose, poses, wsP, wsIK, wsM);
  wss4_kernel<<<FF*BB*DD*NSTRIP*2, 64, 0, stream>>>(frames, keyframe, wsM, out + CV_SIZE);
  final_kernel<<<(BB*HW + 255)/256, 256, 0, stream>>>(wsP, wsIK, out);
}

// Round 7
// 317.067 us; speedup vs baseline: 4.0289x; 4.0289x over previous
//
#include <hip/hip_runtime.h>

#define BB 2
#define FF 2
#define CC 3
#define HH 256
#define WW 512
#define DD 32
#define HW (HH*WW)
#define CV_SIZE (BB*DD*HW)

#define SH 16                 // output rows per block
#define NSTRIP (HH/SH)        // 16
#define HALFW 256             // columns per wave (half image width)
#define INV9 (1.0f/9.0f)
#define C1f 1e-4f
#define C2f 9e-4f

__device__ __forceinline__ int refl(int i, int n) { return i < 0 ? -i : (i >= n ? 2*n-2-i : i); }

// 4x4 Gauss-Jordan inverse with partial pivoting (f32, matches jnp.linalg.inv)
__device__ void inv4(const float* m, float* out) {
  float a[4][8];
  for (int i = 0; i < 4; ++i)
    for (int j = 0; j < 4; ++j) { a[i][j] = m[i*4+j]; a[i][j+4] = (i==j) ? 1.f : 0.f; }
  for (int col = 0; col < 4; ++col) {
    int piv = col; float best = fabsf(a[col][col]);
    for (int r = col+1; r < 4; ++r) { float v = fabsf(a[r][col]); if (v > best) { best = v; piv = r; } }
    if (piv != col) for (int j = 0; j < 8; ++j) { float t = a[col][j]; a[col][j] = a[piv][j]; a[piv][j] = t; }
    float invd = 1.0f / a[col][col];
    for (int j = 0; j < 8; ++j) a[col][j] *= invd;
    for (int r = 0; r < 4; ++r) {
      if (r == col) continue;
      float f = a[r][col];
      for (int j = 0; j < 8; ++j) a[r][j] -= f * a[col][j];
    }
  }
  for (int i = 0; i < 4; ++i) for (int j = 0; j < 4; ++j) out[i*4+j] = a[i][j+4];
}

// IK (3x3 inv intrinsics), P (3x4 proj), M[fb][d] = depth*P[:,:3]*IK (+P[:,3] in col 2)
__global__ void setup_kernel(const float* __restrict__ kK, const float* __restrict__ Ks,
                             const float* __restrict__ kpose, const float* __restrict__ poses,
                             float* __restrict__ P, float* __restrict__ IK, float* __restrict__ M) {
  __shared__ float sIK[BB][9];
  __shared__ float sP[FF*BB][12];
  int t = threadIdx.x;
  if (t < BB) {
    float inv[16]; inv4(kK + t*16, inv);
    float* o = IK + t*9;
    float v0=inv[0], v1=inv[1], v2=inv[2], v3=inv[4], v4=inv[5], v5=inv[6], v6=inv[8], v7=inv[9], v8=inv[10];
    o[0]=v0;o[1]=v1;o[2]=v2;o[3]=v3;o[4]=v4;o[5]=v5;o[6]=v6;o[7]=v7;o[8]=v8;
    sIK[t][0]=v0;sIK[t][1]=v1;sIK[t][2]=v2;sIK[t][3]=v3;sIK[t][4]=v4;sIK[t][5]=v5;sIK[t][6]=v6;sIK[t][7]=v7;sIK[t][8]=v8;
  }
  if (t >= 32 && t < 32 + FF*BB) {
    int i = t - 32;               // i = f*BB + b
    int b = i % BB;
    float ip[16]; inv4(poses + i*16, ip);
    float T[16];
    for (int r = 0; r < 4; ++r)
      for (int c = 0; c < 4; ++c) {
        float s = 0.f;
        for (int k = 0; k < 4; ++k) s += ip[r*4+k] * kpose[b*16 + k*4 + c];
        T[r*4+c] = s;
      }
    for (int r = 0; r < 3; ++r)
      for (int c = 0; c < 4; ++c) {
        float s = 0.f;
        for (int k = 0; k < 4; ++k) s += Ks[i*16 + r*4 + k] * T[k*4 + c];
        P[i*12 + r*4 + c] = s;
        sP[i][r*4+c] = s;
      }
  }
  __syncthreads();
  if (t < FF*BB*DD) {             // 128 matrices
    int fb = t / DD, d = t % DD, b = fb % BB;
    const float invd0 = 1.0f/3.0f;
    const float step  = (0.0125f - (1.0f/3.0f)) / 31.0f;
    float depth = 1.0f / (invd0 + step * (float)d);
    for (int i = 0; i < 3; ++i)
      for (int j = 0; j < 3; ++j) {
        float s = sP[fb][i*4+0]*sIK[b][0*3+j] + sP[fb][i*4+1]*sIK[b][1*3+j] + sP[fb][i*4+2]*sIK[b][2*3+j];
        float mv = depth*s + ((j==2) ? sP[fb][i*4+3] : 0.f);
        M[t*12 + i*3 + j] = mv;
      }
  }
}

struct F3 { float v[CC]; };

// bilinear-sample one column (3 channels) at projected position; returns value+0.5
__device__ __forceinline__ F3 sample_col(const float* __restrict__ frame,
    float m00, float m10, float m20, float b0, float b1, float b2, float fw) {
  float cp0 = fmaf(m00, fw, b0);
  float cp1 = fmaf(m10, fw, b1);
  float cp2 = fmaf(m20, fw, b2);
  float den = cp2 + 1e-7f;
  float rd = __builtin_amdgcn_rcpf(den);
  float px = cp0*rd, py = cp1*rd;
  float gx = fminf(fmaxf((px*(1.0f/511.0f) - 0.5f)*2.0f, -2.0f), 2.0f);
  float gy = fminf(fmaxf((py*(1.0f/255.0f) - 0.5f)*2.0f, -2.0f), 2.0f);
  float x = (gx + 1.0f)*((float)WW*0.5f) - 0.5f;
  float y = (gy + 1.0f)*((float)HH*0.5f) - 0.5f;
  float x0f = floorf(x), y0f = floorf(y);
  float x1f = x0f + 1.f, y1f = y0f + 1.f;
  float wa = (x1f-x)*(y1f-y);
  float wb = (x1f-x)*(y-y0f);
  float wc = (x-x0f)*(y1f-y);
  float wd = (x-x0f)*(y-y0f);
  bool vx0 = (x0f >= 0.f) && (x0f <= (float)(WW-1));
  bool vx1 = (x1f >= 0.f) && (x1f <= (float)(WW-1));
  bool vy0 = (y0f >= 0.f) && (y0f <= (float)(HH-1));
  bool vy1 = (y1f >= 0.f) && (y1f <= (float)(HH-1));
  int xi0 = (int)fminf(fmaxf(x0f, 0.f), (float)(WW-1));
  int xi1 = (int)fminf(fmaxf(x1f, 0.f), (float)(WW-1));
  int yi0 = (int)fminf(fmaxf(y0f, 0.f), (float)(HH-1));
  int yi1 = (int)fminf(fmaxf(y1f, 0.f), (float)(HH-1));
  int i00 = yi0*WW + xi0, i01 = yi1*WW + xi0;
  int i10 = yi0*WW + xi1, i11 = yi1*WW + xi1;
  F3 o;
  #pragma unroll
  for (int c = 0; c < CC; ++c) {
    const float* im = frame + c*HW;
    float va = (vx0 && vy0) ? im[i00] : 0.f;
    float vb2 = (vx0 && vy1) ? im[i01] : 0.f;
    float vc2 = (vx1 && vy0) ? im[i10] : 0.f;
    float vd2 = (vx1 && vy1) ? im[i11] : 0.f;
    o.v[c] = fmaf(va, wa, fmaf(vb2, wb, fmaf(vc2, wc, vd2*wd))) + 0.5f;
  }
  return o;
}

__device__ __forceinline__ float ssim_term(float hx, float hxx, float hxy, float mu_y, float sg_y) {
  float mux = hx*INV9;
  float sigx = fmaf(-mux, mux, hxx*INV9);
  float sigxy = fmaf(-mux, mu_y, hxy*INV9);
  float nn  = (2.f*mux*mu_y + C1f) * (2.f*sigxy + C2f);
  float ddn = fmaf(mux, mux, fmaf(mu_y, mu_y, C1f)) * ((sigx + sg_y) + C2f);
  float v = (1.f - nn*__builtin_amdgcn_rcpf(ddn))*0.5f;
  return fminf(fmaxf(v, 0.f), 1.f);
}

// Fused warp+SSIM+box-sum: one 64-lane wave per (fb, d, strip, half). No LDS, no barriers.
// x AND keyframe-y rolling windows in registers (1 new row of each per iter);
// mu_y/sigma_y computed INLINE from the y window (no precomputed arrays, no re-reads).
// __launch_bounds__(64, 2): cap 256 VGPR (no spill; live state ~150) — the (64,3)/(64,4)
// variants forced VGPR 84/64 and spilled the windows to scratch (GBs of HBM traffic).
__global__ __launch_bounds__(64, 2) void wss4_kernel(
    const float* __restrict__ frames, const float* __restrict__ keyframe,
    const float* __restrict__ M, float* __restrict__ sadout) {
  int bid = blockIdx.x;
  int half  = bid & 1;
  int d     = (bid >> 1) & (DD-1);
  int strip = (bid >> 6) & (NSTRIP-1);
  int fb    = bid >> 10;
  int b = fb % BB;
  int h0 = strip * SH;
  int l = threadIdx.x;
  int w0 = half*HALFW + l*4;
  int hc = half ? (255 - l) : (319 - l);   // halo col: meaningful lanes {0,1} / {62,63}

  const float* Mp = M + (fb*DD + d)*12;
  float m00=Mp[0], m01=Mp[1], m02=Mp[2];
  float m10=Mp[3], m11=Mp[4], m12=Mp[5];
  float m20=Mp[6], m21=Mp[7], m22=Mp[8];
  const float* frame = frames + (size_t)fb*CC*HW;
  const float* kfb   = keyframe + (size_t)b*CC*HW;
  float* sadp = sadout + (size_t)(fb*DD + d)*HW;

  float xr[CC][3][4], yr[CC][3][4];   // rolling windows (rows refl(r-1), refl(r), refl(r+1))
  float hxr[CC][3],   hyr[CC][3];     // halo col rolling windows
  float df[3][4], hdf[3];
  #pragma unroll
  for (int k = 0; k < 4; ++k) { df[0][k]=0.f; df[1][k]=0.f; df[2][k]=0.f; }
  hdf[0]=0.f; hdf[1]=0.f; hdf[2]=0.f;

  float fwk[4], fhc = (float)hc;
  #pragma unroll
  for (int k = 0; k < 4; ++k) fwk[k] = (float)(w0 + k);

#define SAMPLE_ROW(slot, hrarg) do { \
    int hr_ = (hrarg); \
    float fh_ = (float)hr_; \
    float b0_ = fmaf(m01, fh_, m02); \
    float b1_ = fmaf(m11, fh_, m12); \
    float b2_ = fmaf(m21, fh_, m22); \
    _Pragma("unroll") \
    for (int c_ = 0; c_ < CC; ++c_) { \
      const float4 yv_ = *(const float4*)(kfb + c_*HW + hr_*WW + w0); \
      yr[c_][slot][0] = yv_.x + 0.5f; yr[c_][slot][1] = yv_.y + 0.5f; \
      yr[c_][slot][2] = yv_.z + 0.5f; yr[c_][slot][3] = yv_.w + 0.5f; \
      hyr[c_][slot] = kfb[c_*HW + hr_*WW + hc] + 0.5f; \
    } \
    _Pragma("unroll") \
    for (int k_ = 0; k_ < 4; ++k_) { \
      F3 s_ = sample_col(frame, m00, m10, m20, b0_, b1_, b2_, fwk[k_]); \
      xr[0][slot][k_] = s_.v[0]; xr[1][slot][k_] = s_.v[1]; xr[2][slot][k_] = s_.v[2]; \
    } \
    { F3 s_ = sample_col(frame, m00, m10, m20, b0_, b1_, b2_, fhc); \
      hxr[0][slot] = s_.v[0]; hxr[1][slot] = s_.v[1]; hxr[2][slot] = s_.v[2]; } \
  } while (0)

// horizontal 3-sum for main 4 cols + halo col (seam via halo, image edges via reflect)
#define HS(v, hv, o, oh) do { \
    float L_ = __shfl_up((v)[3], 1); \
    float R_ = __shfl_down((v)[0], 1); \
    if (l == 0)  L_ = half ? (hv) : (v)[1]; \
    if (l == 63) R_ = half ? (v)[2] : (hv); \
    float p01_ = (v)[0]+(v)[1], p12_ = (v)[1]+(v)[2], p23_ = (v)[2]+(v)[3]; \
    (o)[0] = L_ + p01_; (o)[1] = p01_ + (v)[2]; \
    (o)[2] = p12_ + (v)[3]; (o)[3] = p23_ + R_; \
    float hL_ = half ? __shfl_down((hv), 1) : (v)[3]; \
    float hR_ = half ? (v)[0] : __shfl_up((hv), 1); \
    (oh) = (hL_ + (hv)) + hR_; \
  } while (0)

  SAMPLE_ROW(0, refl(h0-2, HH));
  SAMPLE_ROW(1, refl(h0-1, HH));

#define STORE_SAD(srow, VB, HVB) do { \
    float Lb_ = __shfl_up((VB)[3], 1); \
    float Rb_ = __shfl_down((VB)[0], 1); \
    if (l == 0)  Lb_ = half ? (HVB) : 0.f; \
    if (l == 63) Rb_ = half ? 0.f : (HVB); \
    float p01_ = (VB)[0]+(VB)[1], p12_ = (VB)[1]+(VB)[2], p23_ = (VB)[2]+(VB)[3]; \
    float4 o_; \
    o_.x = (Lb_ + p01_)*INV9; \
    o_.y = (p01_ + (VB)[2])*INV9; \
    o_.z = (p12_ + (VB)[3])*INV9; \
    o_.w = (p23_ + Rb_)*INV9; \
    *(float4*)(sadp + (size_t)(srow)*WW + w0) = o_; \
  } while (0)

  #pragma unroll 1
  for (int i = 0; i < SH+2; ++i) {
    int r = h0 - 1 + i;
    // ---- sample row r+1 (window becomes rows r-1, r, r+1) ----
    SAMPLE_ROW(2, refl(r+1, HH));

    // ---- box sum for sad row r-2 (df window rows r-3..r-1, pre-rotation) ----
    int s = r - 2;
    if (s >= h0) {
      float vb[4];
      #pragma unroll
      for (int k = 0; k < 4; ++k) vb[k] = (df[0][k] + df[1][k]) + df[2][k];
      float hvb = (hdf[0] + hdf[1]) + hdf[2];
      STORE_SAD(s, vb, hvb);
    }

    // ---- rotate df; compute diff row r (per-channel, inline y-stats) ----
    #pragma unroll
    for (int k = 0; k < 4; ++k) { df[0][k] = df[1][k]; df[1][k] = df[2][k]; }
    hdf[0] = hdf[1]; hdf[1] = hdf[2];
    float nd[4] = {0.f,0.f,0.f,0.f};
    float hnd = 0.f;
    if (r >= 0 && r < HH) {
      #pragma unroll
      for (int c = 0; c < CC; ++c) {
        // vertical sums (x, x^2, x*y, y, y^2)
        float vsx[4], vsxx[4], vsxy[4], vsy[4], vsyy[4];
        #pragma unroll
        for (int k = 0; k < 4; ++k) {
          float x0 = xr[c][0][k], x1 = xr[c][1][k], x2 = xr[c][2][k];
          float y0 = yr[c][0][k], y1 = yr[c][1][k], y2 = yr[c][2][k];
          vsx[k]  = (x0 + x1) + x2;
          vsxx[k] = fmaf(x2, x2, fmaf(x1, x1, x0*x0));
          vsxy[k] = fmaf(x2, y2, fmaf(x1, y1, x0*y0));
          vsy[k]  = (y0 + y1) + y2;
          vsyy[k] = fmaf(y2, y2, fmaf(y1, y1, y0*y0));
        }
        float hx0=hxr[c][0], hx1=hxr[c][1], hx2=hxr[c][2];
        float hy0=hyr[c][0], hy1=hyr[c][1], hy2=hyr[c][2];
        float hvx  = (hx0 + hx1) + hx2;
        float hvxx = fmaf(hx2, hx2, fmaf(hx1, hx1, hx0*hx0));
        float hvxy = fmaf(hx2, hy2, fmaf(hx1, hy1, hx0*hy0));
        float hvy  = (hy0 + hy1) + hy2;
        float hvyy = fmaf(hy2, hy2, fmaf(hy1, hy1, hy0*hy0));

        // horizontal 3-sums
        float hsx[4], hsxx[4], hsxy[4], hsy[4], hsyy[4];
        float hhx, hhxx, hhxy, hhy, hhyy;
        HS(vsx,  hvx,  hsx,  hhx);
        HS(vsxx, hvxx, hsxx, hhxx);
        HS(vsxy, hvxy, hsxy, hhxy);
        HS(vsy,  hvy,  hsy,  hhy);
        HS(vsyy, hvyy, hsyy, hhyy);

        float cwc = (c==0) ? (5.f/32.f) : ((c==1) ? (16.f/32.f) : (11.f/32.f));
        #pragma unroll
        for (int k = 0; k < 4; ++k) {
          float mu_y = hsy[k]*INV9;
          float sg_y = fmaf(-mu_y, mu_y, hsyy[k]*INV9);
          nd[k] = fmaf(cwc, ssim_term(hsx[k], hsxx[k], hsxy[k], mu_y, sg_y), nd[k]);
        }
        float hmu = hhy*INV9;
        float hsg = fmaf(-hmu, hmu, hhyy*INV9);
        hnd = fmaf(cwc, ssim_term(hhx, hhxx, hhxy, hmu, hsg), hnd);
      }
    }
    df[2][0]=nd[0]; df[2][1]=nd[1]; df[2][2]=nd[2]; df[2][3]=nd[3];
    hdf[2] = hnd;

    // ---- rotate x/y windows ----
    #pragma unroll
    for (int c = 0; c < CC; ++c) {
      #pragma unroll
      for (int k = 0; k < 4; ++k) {
        xr[c][0][k]=xr[c][1][k]; xr[c][1][k]=xr[c][2][k];
        yr[c][0][k]=yr[c][1][k]; yr[c][1][k]=yr[c][2][k];
      }
      hxr[c][0]=hxr[c][1]; hxr[c][1]=hxr[c][2];
      hyr[c][0]=hyr[c][1]; hyr[c][1]=hyr[c][2];
    }
  }

  // ---- tail: sad row h0+SH-1 from df rows h0+SH-2..h0+SH ----
  {
    float vb[4];
    #pragma unroll
    for (int k = 0; k < 4; ++k) vb[k] = (df[0][k] + df[1][k]) + df[2][k];
    float hvb = (hdf[0] + hdf[1]) + hdf[2];
    STORE_SAD(h0+SH-1, vb, hvb);
  }
}

struct Proj { float x, y; };

__device__ __forceinline__ Proj project(const float* __restrict__ Pm,
                                        float camx, float camy, float camz, int d) {
  const float invd0 = 1.0f/3.0f;
  const float step  = (0.0125f - (1.0f/3.0f)) / 31.0f;
  float depth = 1.0f / (invd0 + step * (float)d);
  float X = depth*camx, Y = depth*camy, Z = depth*camz;
  float cp0 = Pm[0]*X + Pm[1]*Y + Pm[2]*Z  + Pm[3];
  float cp1 = Pm[4]*X + Pm[5]*Y + Pm[6]*Z  + Pm[7];
  float cp2 = Pm[8]*X + Pm[9]*Y + Pm[10]*Z + Pm[11];
  float den = cp2 + 1e-7f;
  float px = cp0 / den;
  float py = cp1 / den;
  float gx = px / (float)(WW-1);
  float gy = py / (float)(HH-1);
  gx = fminf(fmaxf((gx - 0.5f)*2.0f, -2.0f), 2.0f);
  gy = fminf(fmaxf((gy - 0.5f)*2.0f, -2.0f), 2.0f);
  Proj pr;
  pr.x = (gx + 1.0f) * ((float)WW*0.5f) - 0.5f;
  pr.y = (gy + 1.0f) * ((float)HH*0.5f) - 0.5f;
  return pr;
}

__device__ __forceinline__ float borderVal(float xif, float yif) {
  if (!((xif >= 0.f) && (xif <= (float)(WW-1)) && (yif >= 0.f) && (yif <= (float)(HH-1)))) return 0.f;
  int xi = (int)xif, yi = (int)yif;
  return (xi >= 2 && xi < WW-2 && yi >= 2 && yi < HH-2) ? 1.f : 0.f;
}

// Fused mask + weight + cost-volume + sfcv finalize. One thread = one (b, pixel).
__global__ __launch_bounds__(256) void final_kernel(
    const float* __restrict__ P, const float* __restrict__ IK,
    float* __restrict__ out) {
  int idx = blockIdx.x*blockDim.x + threadIdx.x;
  if (idx >= BB*HW) return;
  int p = idx % HW;
  int b = idx / HW;
  int w = p % WW, h = p / WW;
  float* sadbase = out + CV_SIZE;
  bool inb = (w >= 2 && w < WW-2 && h >= 2 && h < HH-2);

  float fw = (float)w, fh = (float)h;
  const float* ik = IK + b*9;
  float camx = ik[0]*fw + ik[1]*fh + ik[2];
  float camy = ik[3]*fw + ik[4]*fh + ik[5];
  float camz = ik[6]*fw + ik[7]*fh + ik[8];

  float cv[DD];
  #pragma unroll
  for (int d = 0; d < DD; ++d) cv[d] = 0.f;
  float wsum = 0.f;

  for (int f = 0; f < FF; ++f) {
    int fb = f*BB + b;
    const float* Pm = P + fb*12;
    bool ok = true;
    for (int d = 0; d < DD; ++d) {
      Proj pr = project(Pm, camx, camy, camz, d);
      float x = pr.x, y = pr.y;
      float x0f = floorf(x), y0f = floorf(y);
      float x1f = x0f+1.f, y1f = y0f+1.f;
      float wa = (x1f-x)*(y1f-y);
      float wb = (x1f-x)*(y-y0f);
      float wc = (x-x0f)*(y1f-y);
      float wd = (x-x0f)*(y-y0f);
      float m = borderVal(x0f,y0f)*wa + borderVal(x0f,y1f)*wb +
                borderVal(x1f,y0f)*wc + borderVal(x1f,y1f)*wd;
      ok = ok && (m != 0.f);
    }
    float wmask = (inb && ok) ? 1.f : 0.f;

    float* sfb = sadbase + (size_t)fb*DD*HW + p;
    float sv[DD];
    float mn = 3.0e38f;
    #pragma unroll
    for (int d = 0; d < DD; ++d) { sv[d] = sfb[(size_t)d*HW]; mn = fminf(mn, sv[d]); }
    float s = 0.f;
    #pragma unroll
    for (int d = 0; d < DD; ++d) { float tt = sv[d] - mn; s += __expf(-10.f*tt*tt); }
    float wt = (1.f - (s - 1.f)/31.f) * wmask;
    wsum += wt;
    #pragma unroll
    for (int d = 0; d < DD; ++d) {
      cv[d] += sv[d]*wt;
      sfb[(size_t)d*HW] = (1.f - 2.f*sv[d]) * wmask;   // sfcv in place
    }
  }
  #pragma unroll
  for (int d = 0; d < DD; ++d)
    out[((size_t)b*DD + d)*HW + p] = (wsum == 0.f) ? 0.f : 1.f - 2.f*cv[d]/wsum;
}

extern "C" void kernel_launch(void* const* d_in, const int* in_sizes, int n_in,
                              void* d_out, int out_size, void* d_ws, size_t ws_size,
                              hipStream_t stream) {
  const float* keyframe = (const float*)d_in[0];
  const float* frames   = (const float*)d_in[1];
  const float* kK       = (const float*)d_in[2];
  const float* Ks       = (const float*)d_in[3];
  const float* kpose    = (const float*)d_in[4];
  const float* poses    = (const float*)d_in[5];
  float* out = (float*)d_out;

  float* wsP   = (float*)d_ws;            // 48 floats (pad 64)
  float* wsIK  = wsP + 64;                // 18 floats (pad 64)
  float* wsM   = wsIK + 64;               // 128*12 floats

  setup_kernel<<<1, 128, 0, stream>>>(kK, Ks, kpose, poses, wsP, wsIK, wsM);
  wss4_kernel<<<FF*BB*DD*NSTRIP*2, 64, 0, stream>>>(frames, keyframe, wsM, out + CV_SIZE);
  final_kernel<<<(BB*HW + 255)/256, 256, 0, stream>>>(wsP, wsIK, out);
}